// Round 5
// baseline (173.524 us; speedup 1.0000x reference)
//
#include <hip/hip_runtime.h>

// LoopHead: node MLP (32->64->32) then edge decoder (gather/concat -> 64 -> 1)
// Wire dtypes per the reference: fp32 tensors, int32 edge_index, fp32 out.
// R9  = R7 + register prefetch of NEXT iteration's 4 edge indices.
// R10 = edge grid 2048 (neutral -> not TLP-bound).
// R12 = bias-as-C-in + byte-offset addressing (neutral -> not VALU-bound).
// R13 = LDS gather pipeline (REGRESSED: occupancy drop + vmcnt(0) store
//       serialization). REVERTED.
// Conclusion from R10/R12/R13 invariants: edge kernel rides the random-64B
// fabric ceiling (~2.8 TB/s; dur == FETCH/2.8TB/s in every config; z_loop
// 6.4MB > 4MB per-XCD L2 -> 38% capacity miss = measured HBM traffic).
// R14: int8 z_loop + per-node scale (table 3.2MB + 400KB -> L2-resident).
//      Gather bytes halve; HBM-side fetch collapses to eidx + first-touch.
//      Dequant in-register to bf16 frags; weights/MFMAs stay bf16 so only
//      z carries quantization error (predicted absmax ~2-3x of 0.0234).

typedef short bfrag4 __attribute__((ext_vector_type(4)));  // 4 bf16 (x16 frag)
typedef short s16x8  __attribute__((ext_vector_type(8)));  // 8 bf16 (x32 frag)
typedef float f32x4v __attribute__((ext_vector_type(4)));  // fp32 x4

#define N_NODES 100000
#define N_EDGES 3200000

__device__ __forceinline__ unsigned short f2bf(float f) {
    unsigned int i = __float_as_uint(f);
    unsigned int r = i + 0x7FFFu + ((i >> 16) & 1u);  // RNE
    return (unsigned short)(r >> 16);
}

__device__ __forceinline__ bfrag4 cvt4(float x0, float x1, float x2, float x3) {
    bfrag4 v;
    v[0] = (short)f2bf(x0);
    v[1] = (short)f2bf(x1);
    v[2] = (short)f2bf(x2);
    v[3] = (short)f2bf(x3);
    return v;
}

// dequantize 8 packed int8 (one 8B gather) * scale -> 8 bf16 (B-fragment half)
__device__ __forceinline__ s16x8 dq8(long g, float s) {
    int lo = (int)g;
    int hi = (int)(g >> 32);
    s16x8 o;
#pragma unroll
    for (int j = 0; j < 4; ++j) {
        int bj = (lo << (24 - 8 * j)) >> 24;   // sign-extended byte j
        o[j] = (short)f2bf((float)bj * s);
    }
#pragma unroll
    for (int j = 0; j < 4; ++j) {
        int bj = (hi << (24 - 8 * j)) >> 24;
        o[4 + j] = (short)f2bf((float)bj * s);
    }
    return o;
}

// ---------------- Kernel 1: node projection -> z8 (int8 [N,32] + scale) ----
// Stages 1-2 are the proven bf16 MFMA pipeline; epilogue now quantizes each
// node row to int8 with a per-row symmetric scale (rowmax/127).
__global__ __launch_bounds__(256) void node_proj_kernel(
    const float* __restrict__ z_mod,   // [N,32] fp32
    const float* __restrict__ w1,      // [32,64] row-major (k,n)
    const float* __restrict__ b1,      // [64]
    const float* __restrict__ w2,      // [64,32] row-major (k,n)
    const float* __restrict__ b2,      // [32]
    char*  __restrict__ z8,            // [N,32] int8 out (workspace)
    float* __restrict__ scales)        // [N] fp32 out (workspace)
{
    __shared__ unsigned short hbuf[4][16 * 72];

    const int tid  = threadIdx.x;
    const int wave = tid >> 6;
    const int lane = tid & 63;
    const int quad = lane >> 4;
    const int col  = lane & 15;

    bfrag4 bw1[2][4];   // stage 1: K=32 (2 steps), N=64 (4 n-tiles)
    float  bias1[4];
    for (int t = 0; t < 4; ++t) {
        const int n = col + 16 * t;
        for (int s = 0; s < 2; ++s)
            for (int j = 0; j < 4; ++j)
                bw1[s][t][j] = (short)f2bf(w1[(s * 16 + quad * 4 + j) * 64 + n]);
        bias1[t] = b1[n];
    }
    bfrag4 bw2[4][2];   // stage 2: K=64 (4 steps), N=32 (2 n-tiles)
    float  bias2[2];
    for (int t = 0; t < 2; ++t) {
        const int n = col + 16 * t;
        for (int s = 0; s < 4; ++s)
            for (int j = 0; j < 4; ++j)
                bw2[s][t][j] = (short)f2bf(w2[(s * 16 + quad * 4 + j) * 32 + n]);
        bias2[t] = b2[n];
    }

    unsigned short* hrow = &hbuf[wave][0];

    const int gwave  = blockIdx.x * 4 + wave;
    const int nwaves = gridDim.x * 4;
    const int ntiles = N_NODES / 16;   // 6250, exact

    for (int tile = gwave; tile < ntiles; tile += nwaves) {
        const int node0 = tile * 16;
        const float* zrow = z_mod + (size_t)(node0 + col) * 32;

        f32x4v za0 = *(const f32x4v*)(zrow + 0 * 16 + quad * 4);
        f32x4v za1 = *(const f32x4v*)(zrow + 1 * 16 + quad * 4);
        bfrag4 a10 = cvt4(za0[0], za0[1], za0[2], za0[3]);
        bfrag4 a11 = cvt4(za1[0], za1[1], za1[2], za1[3]);

        f32x4v acc[4];
        for (int t = 0; t < 4; ++t) {
            f32x4v c = {bias1[t], bias1[t], bias1[t], bias1[t]};
            c = __builtin_amdgcn_mfma_f32_16x16x16bf16_1k(a10, bw1[0][t], c, 0, 0, 0);
            c = __builtin_amdgcn_mfma_f32_16x16x16bf16_1k(a11, bw1[1][t], c, 0, 0, 0);
            acc[t] = c;
        }

        for (int t = 0; t < 4; ++t)
            for (int r = 0; r < 4; ++r) {
                float v = acc[t][r];
                v = v > 0.f ? v : 0.f;
                hrow[(quad * 4 + r) * 72 + (col + 16 * t)] = f2bf(v);
            }
        asm volatile("" ::: "memory");

        f32x4v acc2[2];
        for (int t = 0; t < 2; ++t)
            acc2[t] = (f32x4v){bias2[t], bias2[t], bias2[t], bias2[t]};
        for (int s = 0; s < 4; ++s) {
            bfrag4 a2 = *(const bfrag4*)(hrow + col * 72 + s * 16 + quad * 4);
            for (int t = 0; t < 2; ++t)
                acc2[t] = __builtin_amdgcn_mfma_f32_16x16x16bf16_1k(a2, bw2[s][t], acc2[t], 0, 0, 0);
        }
        asm volatile("" ::: "memory");

        // ---- int8 quantization epilogue ----
        // lane holds rows node0+quad*4+r (r=0..3) at cols {col, col+16}.
        // rowmax: butterfly over the 16 col-lanes (masks 1,2,4,8).
        float am[4];
        for (int r = 0; r < 4; ++r)
            am[r] = fmaxf(fabsf(acc2[0][r]), fabsf(acc2[1][r]));
        for (int mask = 1; mask <= 8; mask <<= 1)
            for (int r = 0; r < 4; ++r)
                am[r] = fmaxf(am[r], __shfl_xor(am[r], mask, 64));

        char* hb = (char*)hrow;   // reuse hbuf as [16][32] byte buffer
        for (int r = 0; r < 4; ++r) {
            const float inv = 127.f / fmaxf(am[r], 1e-30f);
            for (int t = 0; t < 2; ++t) {
                int q = (int)rintf(acc2[t][r] * inv);
                hb[(quad * 4 + r) * 32 + (col + 16 * t)] = (char)q;
            }
        }
        if (col == 0)
            for (int r = 0; r < 4; ++r)
                scales[node0 + quad * 4 + r] = am[r] * (1.f / 127.f);
        asm volatile("" ::: "memory");

        // coalesced 8B-per-lane store of the 16x32 int8 tile
        *(unsigned long long*)(z8 + (size_t)node0 * 32 + lane * 8) =
            *(const unsigned long long*)(hb + lane * 8);
        asm volatile("" ::: "memory");
    }
}

// ---------------- Kernel 2: edge decoder (int8 gathers, bf16 MFMA) ---------
__global__ __launch_bounds__(256) void edge_dec_kernel(
    const int*   __restrict__ eidx,     // [2, E] int32
    const char*  __restrict__ z8,       // [N,32] int8
    const float* __restrict__ scales,   // [N] fp32
    const float* __restrict__ dw1,      // [64,64] row-major (k,n)
    const float* __restrict__ db1,      // [64]
    const float* __restrict__ dw2,      // [64]
    const float* __restrict__ db2,      // [1]
    float* __restrict__ out)            // [E] fp32
{
    const int tid  = threadIdx.x;
    const int lane = tid & 63;
    const int quad = lane >> 4;
    const int col  = lane & 15;

    // A-frags = dw1^T tiles: aw[s][mt] holds A[m=16mt+col][k=32s+quad*8+j]
    s16x8 aw[2][4];
    f32x4v bias1v[4];    // [mt] = db1[16mt + quad*4 + r], pre-packed as C-in
    float  w2v[4][4];    // [mt][r] = dw2[16mt + quad*4 + r]
    for (int mt = 0; mt < 4; ++mt) {
        const int h = 16 * mt + col;
        for (int s = 0; s < 2; ++s)
            for (int j = 0; j < 8; ++j)
                aw[s][mt][j] = (short)f2bf(dw1[(32 * s + quad * 8 + j) * 64 + h]);
        for (int r = 0; r < 4; ++r) {
            bias1v[mt][r] = db1[16 * mt + quad * 4 + r];
            w2v[mt][r]    = dw2[16 * mt + quad * 4 + r];
        }
    }
    const float bias2 = db2[0];

    const int gwave  = blockIdx.x * 4 + (tid >> 6);
    const int nwaves = gridDim.x * 4;     // 8192
    const int npairs = N_EDGES / 32;      // 100000, exact

    // prefetch node indices for the first iteration (gwave < npairs always)
    int sA = eidx[gwave * 32 + col];
    int sB = eidx[gwave * 32 + 16 + col];
    int dA = eidx[N_EDGES + gwave * 32 + col];
    int dB = eidx[N_EDGES + gwave * 32 + 16 + col];

    for (int p = gwave; p < npairs; p += nwaves) {
        const int e0 = p * 32;

        // 8B row-half gathers (L2-resident 3.2MB table) + per-node scales
        long gA0 = *(const long*)(z8 + ((size_t)sA << 5) + (quad << 3));
        long gA1 = *(const long*)(z8 + ((size_t)dA << 5) + (quad << 3));
        long gB0 = *(const long*)(z8 + ((size_t)sB << 5) + (quad << 3));
        long gB1 = *(const long*)(z8 + ((size_t)dB << 5) + (quad << 3));
        float scA0 = scales[sA];
        float scA1 = scales[dA];
        float scB0 = scales[sB];
        float scB1 = scales[dB];

        // prefetch NEXT iteration's indices (branchless clamp — always valid)
        const int pn = p + nwaves;
        const int pc = pn < npairs ? pn : gwave;
        sA = eidx[pc * 32 + col];
        sB = eidx[pc * 32 + 16 + col];
        dA = eidx[N_EDGES + pc * 32 + col];
        dB = eidx[N_EDGES + pc * 32 + 16 + col];

        // dequantize to bf16 B-fragments
        s16x8 fA0 = dq8(gA0, scA0);
        s16x8 fA1 = dq8(gA1, scA1);
        s16x8 fB0 = dq8(gB0, scB0);
        s16x8 fB1 = dq8(gB1, scB1);

        // he^T[m=hidden][n=edge]: 4 M-tiles x 2 K-steps per 16 edges.
        f32x4v accA[4], accB[4];
        for (int mt = 0; mt < 4; ++mt) {
            f32x4v c = __builtin_amdgcn_mfma_f32_16x16x32_bf16(aw[0][mt], fA0, bias1v[mt], 0, 0, 0);
            accA[mt] = __builtin_amdgcn_mfma_f32_16x16x32_bf16(aw[1][mt], fA1, c, 0, 0, 0);
        }
        for (int mt = 0; mt < 4; ++mt) {
            f32x4v c = __builtin_amdgcn_mfma_f32_16x16x32_bf16(aw[0][mt], fB0, bias1v[mt], 0, 0, 0);
            accB[mt] = __builtin_amdgcn_mfma_f32_16x16x32_bf16(aw[1][mt], fB1, c, 0, 0, 0);
        }

        // relu + dw2-dot: lane owns 16 hidden units of ONE edge (n=col);
        // in-lane fma then 2-step quad reduce.
        float pA = 0.f, pB = 0.f;
        for (int mt = 0; mt < 4; ++mt)
            for (int r = 0; r < 4; ++r) {
                float vA = accA[mt][r]; vA = vA > 0.f ? vA : 0.f;
                float vB = accB[mt][r]; vB = vB > 0.f ? vB : 0.f;
                pA += vA * w2v[mt][r];
                pB += vB * w2v[mt][r];
            }
        pA += __shfl_xor(pA, 16, 64);
        pA += __shfl_xor(pA, 32, 64);
        pB += __shfl_xor(pB, 16, 64);
        pB += __shfl_xor(pB, 32, 64);

        // lanes 0-15: edge e0+lane (tile A); 16-31: e0+lane (tile B).
        if (lane < 32) {
            float v = (lane < 16 ? pA : pB) + bias2;
            out[e0 + lane] = v;
        }
    }
}

extern "C" void kernel_launch(void* const* d_in, const int* in_sizes, int n_in,
                              void* d_out, int out_size, void* d_ws, size_t ws_size,
                              hipStream_t stream) {
    const float* z_mod = (const float*)d_in[0];
    const int*   eidx  = (const int*)d_in[1];
    const float* w1    = (const float*)d_in[2];
    const float* b1    = (const float*)d_in[3];
    const float* w2    = (const float*)d_in[4];
    const float* b2    = (const float*)d_in[5];
    const float* dw1   = (const float*)d_in[6];
    const float* db1   = (const float*)d_in[7];
    const float* dw2   = (const float*)d_in[8];
    const float* db2   = (const float*)d_in[9];
    float* out = (float*)d_out;

    char*  z8     = (char*)d_ws;                              // 3.2 MB
    float* scales = (float*)((char*)d_ws + (size_t)N_NODES * 32);  // 400 KB

    node_proj_kernel<<<512, 256, 0, stream>>>(z_mod, w1, b1, w2, b2, z8, scales);
    edge_dec_kernel<<<2048, 256, 0, stream>>>(eidx, z8, scales, dw1, db1, dw2, db2, out);
}

// Round 6
// 172.886 us; speedup vs baseline: 1.0037x; 1.0037x over previous
//
#include <hip/hip_runtime.h>

// LoopHead: node MLP (32->64->32) then edge decoder (gather/concat -> 64 -> 1)
// R10 = more waves: neutral. R12 = less VALU: neutral. R13 = LDS pipeline:
// regressed. R14 = int8+scales: FETCH 176->39MB (L2-resident, CONFIRMED) but
// SLOWER (96us) because lane-request count doubled (512/iter vs 256).
// Model fitting all rounds: edge kernel is bound by the per-CU vector-memory
// REQUEST pipe (~1 divergent lane-addr/cy): time tracks lane-requests, not
// bytes, not HBM, not VALU.
// R15: same int8+scale data (absmax 0.03125 proven), restructured gather:
//   - each 32B row fetched by 2 ADJACENT lanes x 16B (same-line pairs
//     coalesce) -> 64 req/instr -> 32 after pair-merge; 2 instr (src,dst).
//   - all 64 scales in ONE instr (64 req) vs 4 instr/256 req.
//   - redistribute to MFMA B-frag layout via 2KB wave-private LDS
//     (ds_write_b128/ds_read_b64, no barriers needed within a wave).
//   ~134 lane-req/iter vs R12's 256 / R14's 512.

typedef short bfrag4 __attribute__((ext_vector_type(4)));  // 4 bf16 (x16 frag)
typedef short s16x8  __attribute__((ext_vector_type(8)));  // 8 bf16 (x32 frag)
typedef float f32x4v __attribute__((ext_vector_type(4)));  // fp32 x4
typedef int   i32x4  __attribute__((ext_vector_type(4)));  // int32 x4 (16B)

#define N_NODES 100000
#define N_EDGES 3200000

__device__ __forceinline__ unsigned short f2bf(float f) {
    unsigned int i = __float_as_uint(f);
    unsigned int r = i + 0x7FFFu + ((i >> 16) & 1u);  // RNE
    return (unsigned short)(r >> 16);
}

__device__ __forceinline__ bfrag4 cvt4(float x0, float x1, float x2, float x3) {
    bfrag4 v;
    v[0] = (short)f2bf(x0);
    v[1] = (short)f2bf(x1);
    v[2] = (short)f2bf(x2);
    v[3] = (short)f2bf(x3);
    return v;
}

// dequantize 8 int8 (one 8B chunk, dims k..k+7) * scale -> 8 bf16 B-frag
// (bit-identical math to R14's dq8 -> absmax must stay 0.03125)
__device__ __forceinline__ s16x8 dq16(long g, float s) {
    const int lo = (int)g;
    const int hi = (int)(g >> 32);
    s16x8 o;
#pragma unroll
    for (int j = 0; j < 4; ++j) {
        int bj = (lo << (24 - 8 * j)) >> 24;   // sign-extended byte j
        o[j] = (short)f2bf((float)bj * s);
    }
#pragma unroll
    for (int j = 0; j < 4; ++j) {
        int bj = (hi << (24 - 8 * j)) >> 24;
        o[4 + j] = (short)f2bf((float)bj * s);
    }
    return o;
}

// ---------------- Kernel 1: node projection -> z8 (int8 [N,32] + scale) ----
// (verbatim R14 version — harness-proven, absmax 0.03125)
__global__ __launch_bounds__(256) void node_proj_kernel(
    const float* __restrict__ z_mod,   // [N,32] fp32
    const float* __restrict__ w1,      // [32,64] row-major (k,n)
    const float* __restrict__ b1,      // [64]
    const float* __restrict__ w2,      // [64,32] row-major (k,n)
    const float* __restrict__ b2,      // [32]
    char*  __restrict__ z8,            // [N,32] int8 out (workspace)
    float* __restrict__ scales)        // [N] fp32 out (workspace)
{
    __shared__ unsigned short hbuf[4][16 * 72];

    const int tid  = threadIdx.x;
    const int wave = tid >> 6;
    const int lane = tid & 63;
    const int quad = lane >> 4;
    const int col  = lane & 15;

    bfrag4 bw1[2][4];   // stage 1: K=32 (2 steps), N=64 (4 n-tiles)
    float  bias1[4];
    for (int t = 0; t < 4; ++t) {
        const int n = col + 16 * t;
        for (int s = 0; s < 2; ++s)
            for (int j = 0; j < 4; ++j)
                bw1[s][t][j] = (short)f2bf(w1[(s * 16 + quad * 4 + j) * 64 + n]);
        bias1[t] = b1[n];
    }
    bfrag4 bw2[4][2];   // stage 2: K=64 (4 steps), N=32 (2 n-tiles)
    float  bias2[2];
    for (int t = 0; t < 2; ++t) {
        const int n = col + 16 * t;
        for (int s = 0; s < 4; ++s)
            for (int j = 0; j < 4; ++j)
                bw2[s][t][j] = (short)f2bf(w2[(s * 16 + quad * 4 + j) * 32 + n]);
        bias2[t] = b2[n];
    }

    unsigned short* hrow = &hbuf[wave][0];

    const int gwave  = blockIdx.x * 4 + wave;
    const int nwaves = gridDim.x * 4;
    const int ntiles = N_NODES / 16;   // 6250, exact

    for (int tile = gwave; tile < ntiles; tile += nwaves) {
        const int node0 = tile * 16;
        const float* zrow = z_mod + (size_t)(node0 + col) * 32;

        f32x4v za0 = *(const f32x4v*)(zrow + 0 * 16 + quad * 4);
        f32x4v za1 = *(const f32x4v*)(zrow + 1 * 16 + quad * 4);
        bfrag4 a10 = cvt4(za0[0], za0[1], za0[2], za0[3]);
        bfrag4 a11 = cvt4(za1[0], za1[1], za1[2], za1[3]);

        f32x4v acc[4];
        for (int t = 0; t < 4; ++t) {
            f32x4v c = {bias1[t], bias1[t], bias1[t], bias1[t]};
            c = __builtin_amdgcn_mfma_f32_16x16x16bf16_1k(a10, bw1[0][t], c, 0, 0, 0);
            c = __builtin_amdgcn_mfma_f32_16x16x16bf16_1k(a11, bw1[1][t], c, 0, 0, 0);
            acc[t] = c;
        }

        for (int t = 0; t < 4; ++t)
            for (int r = 0; r < 4; ++r) {
                float v = acc[t][r];
                v = v > 0.f ? v : 0.f;
                hrow[(quad * 4 + r) * 72 + (col + 16 * t)] = f2bf(v);
            }
        asm volatile("" ::: "memory");

        f32x4v acc2[2];
        for (int t = 0; t < 2; ++t)
            acc2[t] = (f32x4v){bias2[t], bias2[t], bias2[t], bias2[t]};
        for (int s = 0; s < 4; ++s) {
            bfrag4 a2 = *(const bfrag4*)(hrow + col * 72 + s * 16 + quad * 4);
            for (int t = 0; t < 2; ++t)
                acc2[t] = __builtin_amdgcn_mfma_f32_16x16x16bf16_1k(a2, bw2[s][t], acc2[t], 0, 0, 0);
        }
        asm volatile("" ::: "memory");

        // ---- int8 quantization epilogue ----
        float am[4];
        for (int r = 0; r < 4; ++r)
            am[r] = fmaxf(fabsf(acc2[0][r]), fabsf(acc2[1][r]));
        for (int mask = 1; mask <= 8; mask <<= 1)
            for (int r = 0; r < 4; ++r)
                am[r] = fmaxf(am[r], __shfl_xor(am[r], mask, 64));

        char* hb = (char*)hrow;   // reuse hbuf as [16][32] byte buffer
        for (int r = 0; r < 4; ++r) {
            const float inv = 127.f / fmaxf(am[r], 1e-30f);
            for (int t = 0; t < 2; ++t) {
                int q = (int)rintf(acc2[t][r] * inv);
                hb[(quad * 4 + r) * 32 + (col + 16 * t)] = (char)q;
            }
        }
        if (col == 0)
            for (int r = 0; r < 4; ++r)
                scales[node0 + quad * 4 + r] = am[r] * (1.f / 127.f);
        asm volatile("" ::: "memory");

        *(unsigned long long*)(z8 + (size_t)node0 * 32 + lane * 8) =
            *(const unsigned long long*)(hb + lane * 8);
        asm volatile("" ::: "memory");
    }
}

// ---------------- Kernel 2: edge decoder (R15: low-request gathers) --------
__global__ __launch_bounds__(256) void edge_dec_kernel(
    const int*   __restrict__ eidx,     // [2, E] int32
    const char*  __restrict__ z8,       // [N,32] int8
    const float* __restrict__ scales,   // [N] fp32
    const float* __restrict__ dw1,      // [64,64] row-major (k,n)
    const float* __restrict__ db1,      // [64]
    const float* __restrict__ dw2,      // [64]
    const float* __restrict__ db2,      // [1]
    float* __restrict__ out)            // [E] fp32
{
    // wave-private staging: [wave][src/dst][64 lanes * 16B] = 8 KB/block
    __shared__ char xbuf[4][2][1024];

    const int tid  = threadIdx.x;
    const int wave = tid >> 6;
    const int lane = tid & 63;
    const int quad = lane >> 4;
    const int col  = lane & 15;
    const int eh   = lane >> 1;    // z-fetch: edge-in-pair 0..31
    const int hf   = lane & 1;     // z-fetch: which 16B half of the 32B row
    const int ss   = lane >> 5;    // scale-fetch: 0=src, 1=dst
    const int se   = lane & 31;    // scale-fetch: edge-in-pair

    // A-frags = dw1^T tiles: aw[s][mt] holds A[m=16mt+col][k=32s+quad*8+j]
    s16x8 aw[2][4];
    f32x4v bias1v[4];    // [mt] = db1[16mt + quad*4 + r], as MFMA C-in
    float  w2v[4][4];    // [mt][r] = dw2[16mt + quad*4 + r]
    for (int mt = 0; mt < 4; ++mt) {
        const int h = 16 * mt + col;
        for (int s = 0; s < 2; ++s)
            for (int j = 0; j < 8; ++j)
                aw[s][mt][j] = (short)f2bf(dw1[(32 * s + quad * 8 + j) * 64 + h]);
        for (int r = 0; r < 4; ++r) {
            bias1v[mt][r] = db1[16 * mt + quad * 4 + r];
            w2v[mt][r]    = dw2[16 * mt + quad * 4 + r];
        }
    }
    const float bias2 = db2[0];

    const int gwave  = blockIdx.x * 4 + wave;
    const int nwaves = gridDim.x * 4;     // 8192
    const int npairs = N_EDGES / 32;      // 100000, exact

    char* wbS = &xbuf[wave][0][0];
    char* wbD = &xbuf[wave][1][0];

    // ds_read address: consumer (col,quad) needs bytes [quad*8, quad*8+8) of
    // its edge's row; those sit in fetch-lane F = 2*edge + (quad>>1), at
    // byte (quad&1)*8 of F's 16B slot.
    const int rb = (2 * col + (quad >> 1)) * 16 + (quad & 1) * 8;

    // prefetch first iteration's indices (gwave < npairs: 8192 <= 100000)
    int iS = eidx[gwave * 32 + eh];
    int iD = eidx[N_EDGES + gwave * 32 + eh];
    int iC = eidx[ss * N_EDGES + gwave * 32 + se];

    for (int p = gwave; p < npairs; p += nwaves) {
        const int e0 = p * 32;

        // ---- 3 gather instrs: 2x rows (16B/lane, adjacent-pair same-line)
        //      + 1x all 64 scales
        i32x4 vS = *(const i32x4*)(z8 + (size_t)iS * 32 + hf * 16);
        i32x4 vD = *(const i32x4*)(z8 + (size_t)iD * 32 + hf * 16);
        float sc = scales[iC];

        // prefetch NEXT iteration's indices (branchless clamp — always valid)
        const int pn = p + nwaves;
        const int pc = pn < npairs ? pn : gwave;
        iS = eidx[pc * 32 + eh];
        iD = eidx[N_EDGES + pc * 32 + eh];
        iC = eidx[ss * N_EDGES + pc * 32 + se];

        // stage rows to wave-private LDS (in-wave ordering; no barrier)
        *(i32x4*)(wbS + lane * 16) = vS;
        *(i32x4*)(wbD + lane * 16) = vD;

        // read back in B-frag layout (tile B edges live at F+32 -> +512B)
        long pSA = *(const long*)(wbS + rb);
        long pSB = *(const long*)(wbS + 512 + rb);
        long pDA = *(const long*)(wbD + rb);
        long pDB = *(const long*)(wbD + 512 + rb);

        // scales to consumers (frag n=col): src/dst of tile-A/B edge col
        float sA0 = __shfl(sc, col, 64);
        float sB0 = __shfl(sc, 16 + col, 64);
        float sA1 = __shfl(sc, 32 + col, 64);
        float sB1 = __shfl(sc, 48 + col, 64);

        // dequantize to bf16 B-fragments (bit-identical to R14)
        s16x8 gA0 = dq16(pSA, sA0);
        s16x8 gA1 = dq16(pDA, sA1);
        s16x8 gB0 = dq16(pSB, sB0);
        s16x8 gB1 = dq16(pDB, sB1);

        // he^T[m=hidden][n=edge]: 4 M-tiles x 2 K-steps per 16 edges.
        f32x4v accA[4], accB[4];
        for (int mt = 0; mt < 4; ++mt) {
            f32x4v c = __builtin_amdgcn_mfma_f32_16x16x32_bf16(aw[0][mt], gA0, bias1v[mt], 0, 0, 0);
            accA[mt] = __builtin_amdgcn_mfma_f32_16x16x32_bf16(aw[1][mt], gA1, c, 0, 0, 0);
        }
        for (int mt = 0; mt < 4; ++mt) {
            f32x4v c = __builtin_amdgcn_mfma_f32_16x16x32_bf16(aw[0][mt], gB0, bias1v[mt], 0, 0, 0);
            accB[mt] = __builtin_amdgcn_mfma_f32_16x16x32_bf16(aw[1][mt], gB1, c, 0, 0, 0);
        }

        // relu + dw2-dot: lane owns 16 hidden units of ONE edge (n=col);
        // in-lane fma then 2-step quad reduce.
        float pA = 0.f, pB = 0.f;
        for (int mt = 0; mt < 4; ++mt)
            for (int r = 0; r < 4; ++r) {
                float vA = accA[mt][r]; vA = vA > 0.f ? vA : 0.f;
                float vB = accB[mt][r]; vB = vB > 0.f ? vB : 0.f;
                pA += vA * w2v[mt][r];
                pB += vB * w2v[mt][r];
            }
        pA += __shfl_xor(pA, 16, 64);
        pA += __shfl_xor(pA, 32, 64);
        pB += __shfl_xor(pB, 16, 64);
        pB += __shfl_xor(pB, 32, 64);

        // lanes 0-15: edge e0+lane (tile A); 16-31: e0+lane (tile B).
        if (lane < 32) {
            float v = (lane < 16 ? pA : pB) + bias2;
            out[e0 + lane] = v;
        }
    }
}

extern "C" void kernel_launch(void* const* d_in, const int* in_sizes, int n_in,
                              void* d_out, int out_size, void* d_ws, size_t ws_size,
                              hipStream_t stream) {
    const float* z_mod = (const float*)d_in[0];
    const int*   eidx  = (const int*)d_in[1];
    const float* w1    = (const float*)d_in[2];
    const float* b1    = (const float*)d_in[3];
    const float* w2    = (const float*)d_in[4];
    const float* b2    = (const float*)d_in[5];
    const float* dw1   = (const float*)d_in[6];
    const float* db1   = (const float*)d_in[7];
    const float* dw2   = (const float*)d_in[8];
    const float* db2   = (const float*)d_in[9];
    float* out = (float*)d_out;

    char*  z8     = (char*)d_ws;                                   // 3.2 MB
    float* scales = (float*)((char*)d_ws + (size_t)N_NODES * 32);  // 400 KB

    node_proj_kernel<<<512, 256, 0, stream>>>(z_mod, w1, b1, w2, b2, z8, scales);
    edge_dec_kernel<<<2048, 256, 0, stream>>>(eidx, z8, scales, dw1, db1, dw2, db2, out);
}

// Round 7
// 166.862 us; speedup vs baseline: 1.0399x; 1.0361x over previous
//
#include <hip/hip_runtime.h>

// LoopHead: node MLP (32->64->32) then edge decoder (gather/concat -> 64 -> 1)
// Failed theories (counter-verified): TLP (R10 neutral), VALU issue (R12
// neutral), glds pipeline (R13 regressed), HBM bytes (R14: FETCH 176->39MB
// yet slower), request count (R15 neutral + 4.8M LDS conflicts).
// Surviving model: cost ~ distinct random L2 sector-touches per iter
// (~4.6cy/CU hit, ~9.7 miss): R12 = 64 touches (418cy/iter = 68us) ✓,
// R14/R15 = 128 touches (z + SCALES) ~590cy/iter = 91-96us ✓.
// R16: int8 z8 (3.2MB, L2-resident) with R12's exact 4x8B gather shape
//      (64 touches/iter, no z staging) + per-GROUP-of-4-nodes bf16 scales
//      (25000 x 2B = 50KB) PRELOADED INTO LDS -> scale lookups cost zero
//      L2 touches. Group-4 = one quad's rows in the node kernel (3 fmax).
//      Edge grid 768 = exactly 3 blocks/CU @ 50KB LDS.

typedef short bfrag4 __attribute__((ext_vector_type(4)));  // 4 bf16 (x16 frag)
typedef short s16x8  __attribute__((ext_vector_type(8)));  // 8 bf16 (x32 frag)
typedef float f32x4v __attribute__((ext_vector_type(4)));  // fp32 x4
typedef int   i32x4  __attribute__((ext_vector_type(4)));  // int32 x4 (16B)

#define N_NODES 100000
#define N_EDGES 3200000

__device__ __forceinline__ unsigned short f2bf(float f) {
    unsigned int i = __float_as_uint(f);
    unsigned int r = i + 0x7FFFu + ((i >> 16) & 1u);  // RNE
    return (unsigned short)(r >> 16);
}

__device__ __forceinline__ float bf2f(unsigned short b) {
    unsigned int u = ((unsigned int)b) << 16;
    return __uint_as_float(u);
}

__device__ __forceinline__ bfrag4 cvt4(float x0, float x1, float x2, float x3) {
    bfrag4 v;
    v[0] = (short)f2bf(x0);
    v[1] = (short)f2bf(x1);
    v[2] = (short)f2bf(x2);
    v[3] = (short)f2bf(x3);
    return v;
}

// dequantize 8 packed int8 (one 8B gather) * scale -> 8 bf16 (B-frag half)
// (bit-identical per-element math to R14's proven dq8)
__device__ __forceinline__ s16x8 dq8(long g, float s) {
    const int lo = (int)g;
    const int hi = (int)(g >> 32);
    s16x8 o;
#pragma unroll
    for (int j = 0; j < 4; ++j) {
        int bj = (lo << (24 - 8 * j)) >> 24;   // sign-extended byte j
        o[j] = (short)f2bf((float)bj * s);
    }
#pragma unroll
    for (int j = 0; j < 4; ++j) {
        int bj = (hi << (24 - 8 * j)) >> 24;
        o[4 + j] = (short)f2bf((float)bj * s);
    }
    return o;
}

// ---------------- Kernel 1: node projection -> z8 + group-4 scales ---------
__global__ __launch_bounds__(256) void node_proj_kernel(
    const float* __restrict__ z_mod,   // [N,32] fp32
    const float* __restrict__ w1,      // [32,64] row-major (k,n)
    const float* __restrict__ b1,      // [64]
    const float* __restrict__ w2,      // [64,32] row-major (k,n)
    const float* __restrict__ b2,      // [32]
    char*           __restrict__ z8,      // [N,32] int8 out (workspace)
    unsigned short* __restrict__ scg)     // [N/4] bf16 group scales (ws)
{
    __shared__ unsigned short hbuf[4][16 * 72];

    const int tid  = threadIdx.x;
    const int wave = tid >> 6;
    const int lane = tid & 63;
    const int quad = lane >> 4;
    const int col  = lane & 15;

    bfrag4 bw1[2][4];   // stage 1: K=32 (2 steps), N=64 (4 n-tiles)
    float  bias1[4];
    for (int t = 0; t < 4; ++t) {
        const int n = col + 16 * t;
        for (int s = 0; s < 2; ++s)
            for (int j = 0; j < 4; ++j)
                bw1[s][t][j] = (short)f2bf(w1[(s * 16 + quad * 4 + j) * 64 + n]);
        bias1[t] = b1[n];
    }
    bfrag4 bw2[4][2];   // stage 2: K=64 (4 steps), N=32 (2 n-tiles)
    float  bias2[2];
    for (int t = 0; t < 2; ++t) {
        const int n = col + 16 * t;
        for (int s = 0; s < 4; ++s)
            for (int j = 0; j < 4; ++j)
                bw2[s][t][j] = (short)f2bf(w2[(s * 16 + quad * 4 + j) * 32 + n]);
        bias2[t] = b2[n];
    }

    unsigned short* hrow = &hbuf[wave][0];

    const int gwave  = blockIdx.x * 4 + wave;
    const int nwaves = gridDim.x * 4;
    const int ntiles = N_NODES / 16;   // 6250, exact

    for (int tile = gwave; tile < ntiles; tile += nwaves) {
        const int node0 = tile * 16;
        const float* zrow = z_mod + (size_t)(node0 + col) * 32;

        f32x4v za0 = *(const f32x4v*)(zrow + 0 * 16 + quad * 4);
        f32x4v za1 = *(const f32x4v*)(zrow + 1 * 16 + quad * 4);
        bfrag4 a10 = cvt4(za0[0], za0[1], za0[2], za0[3]);
        bfrag4 a11 = cvt4(za1[0], za1[1], za1[2], za1[3]);

        f32x4v acc[4];
        for (int t = 0; t < 4; ++t) {
            f32x4v c = {bias1[t], bias1[t], bias1[t], bias1[t]};
            c = __builtin_amdgcn_mfma_f32_16x16x16bf16_1k(a10, bw1[0][t], c, 0, 0, 0);
            c = __builtin_amdgcn_mfma_f32_16x16x16bf16_1k(a11, bw1[1][t], c, 0, 0, 0);
            acc[t] = c;
        }

        for (int t = 0; t < 4; ++t)
            for (int r = 0; r < 4; ++r) {
                float v = acc[t][r];
                v = v > 0.f ? v : 0.f;
                hrow[(quad * 4 + r) * 72 + (col + 16 * t)] = f2bf(v);
            }
        asm volatile("" ::: "memory");

        f32x4v acc2[2];
        for (int t = 0; t < 2; ++t)
            acc2[t] = (f32x4v){bias2[t], bias2[t], bias2[t], bias2[t]};
        for (int s = 0; s < 4; ++s) {
            bfrag4 a2 = *(const bfrag4*)(hrow + col * 72 + s * 16 + quad * 4);
            for (int t = 0; t < 2; ++t)
                acc2[t] = __builtin_amdgcn_mfma_f32_16x16x16bf16_1k(a2, bw2[s][t], acc2[t], 0, 0, 0);
        }
        asm volatile("" ::: "memory");

        // ---- int8 quantization epilogue: per-GROUP-of-4 scale -------------
        // lane holds rows node0+quad*4+r (r=0..3) -> exactly group
        // node0/4 + quad. rowmax butterfly over 16 col-lanes, then 3 fmax.
        float am[4];
        for (int r = 0; r < 4; ++r)
            am[r] = fmaxf(fabsf(acc2[0][r]), fabsf(acc2[1][r]));
        for (int mask = 1; mask <= 8; mask <<= 1)
            for (int r = 0; r < 4; ++r)
                am[r] = fmaxf(am[r], __shfl_xor(am[r], mask, 64));
        const float gm = fmaxf(fmaxf(am[0], am[1]), fmaxf(am[2], am[3]));
        const float inv = 127.f / fmaxf(gm, 1e-30f);

        char* hb = (char*)hrow;   // reuse hbuf as [16][32] byte buffer
        for (int r = 0; r < 4; ++r)
            for (int t = 0; t < 2; ++t) {
                int q = (int)rintf(acc2[t][r] * inv);
                hb[(quad * 4 + r) * 32 + (col + 16 * t)] = (char)q;
            }
        if (col == 0)
            scg[(node0 >> 2) + quad] = f2bf(gm * (1.f / 127.f));
        asm volatile("" ::: "memory");

        // coalesced 8B-per-lane store of the 16x32 int8 tile
        *(unsigned long long*)(z8 + (size_t)node0 * 32 + lane * 8) =
            *(const unsigned long long*)(hb + lane * 8);
        asm volatile("" ::: "memory");
    }
}

// ---------------- Kernel 2: edge decoder (R16: LDS scales, R12 gathers) ----
__global__ __launch_bounds__(256) void edge_dec_kernel(
    const int*            __restrict__ eidx,   // [2, E] int32
    const char*           __restrict__ z8,     // [N,32] int8
    const unsigned short* __restrict__ scg,    // [N/4] bf16 group scales
    const float*          __restrict__ dw1,    // [64,64] row-major (k,n)
    const float*          __restrict__ db1,    // [64]
    const float*          __restrict__ dw2,    // [64]
    const float*          __restrict__ db2,    // [1]
    float* __restrict__ out)                   // [E] fp32
{
    // all 25000 group scales, staged once per block: 50048 B
    __shared__ i32x4 slds4[3128];
    unsigned short* slds = (unsigned short*)slds4;

    const int tid  = threadIdx.x;
    const int lane = tid & 63;
    const int quad = lane >> 4;
    const int col  = lane & 15;

    // cooperative scale staging (coalesced 16B/thread x ~12 iters)
    for (int i = tid; i < 3128; i += 256)
        slds4[i] = ((const i32x4*)scg)[i];

    // A-frags = dw1^T tiles: aw[s][mt] holds A[m=16mt+col][k=32s+quad*8+j]
    s16x8 aw[2][4];
    f32x4v bias1v[4];    // [mt] = db1[16mt + quad*4 + r], as MFMA C-in
    float  w2v[4][4];    // [mt][r] = dw2[16mt + quad*4 + r]
    for (int mt = 0; mt < 4; ++mt) {
        const int h = 16 * mt + col;
        for (int s = 0; s < 2; ++s)
            for (int j = 0; j < 8; ++j)
                aw[s][mt][j] = (short)f2bf(dw1[(32 * s + quad * 8 + j) * 64 + h]);
        for (int r = 0; r < 4; ++r) {
            bias1v[mt][r] = db1[16 * mt + quad * 4 + r];
            w2v[mt][r]    = dw2[16 * mt + quad * 4 + r];
        }
    }
    const float bias2 = db2[0];

    __syncthreads();   // scales staged

    const int gwave  = blockIdx.x * 4 + (tid >> 6);
    const int nwaves = gridDim.x * 4;     // 3072
    const int npairs = N_EDGES / 32;      // 100000, exact

    const int qoff = quad * 8;            // 8B chunk within the 32B row

    // prefetch first iteration's node indices (gwave < npairs: 3072<=100000)
    int sA = eidx[gwave * 32 + col];
    int sB = eidx[gwave * 32 + 16 + col];
    int dA = eidx[N_EDGES + gwave * 32 + col];
    int dB = eidx[N_EDGES + gwave * 32 + 16 + col];

    for (int p = gwave; p < npairs; p += nwaves) {
        const int e0 = p * 32;

        // 4 independent 8B gathers — R12's proven shape; each 32B row is
        // ONE sector touch shared by its 4 quads. L2-resident table.
        long gA0 = *(const long*)(z8 + sA * 32 + qoff);
        long gA1 = *(const long*)(z8 + dA * 32 + qoff);
        long gB0 = *(const long*)(z8 + sB * 32 + qoff);
        long gB1 = *(const long*)(z8 + dB * 32 + qoff);

        // scales from LDS (broadcast-friendly; zero L2 touches)
        float scA0 = bf2f(slds[sA >> 2]);
        float scA1 = bf2f(slds[dA >> 2]);
        float scB0 = bf2f(slds[sB >> 2]);
        float scB1 = bf2f(slds[dB >> 2]);

        // prefetch NEXT iteration's indices (branchless clamp — always valid)
        const int pn = p + nwaves;
        const int pc = pn < npairs ? pn : gwave;
        sA = eidx[pc * 32 + col];
        sB = eidx[pc * 32 + 16 + col];
        dA = eidx[N_EDGES + pc * 32 + col];
        dB = eidx[N_EDGES + pc * 32 + 16 + col];

        // dequantize to bf16 B-fragments
        s16x8 fA0 = dq8(gA0, scA0);
        s16x8 fA1 = dq8(gA1, scA1);
        s16x8 fB0 = dq8(gB0, scB0);
        s16x8 fB1 = dq8(gB1, scB1);

        // he^T[m=hidden][n=edge]: 4 M-tiles x 2 K-steps per 16 edges.
        f32x4v accA[4], accB[4];
        for (int mt = 0; mt < 4; ++mt) {
            f32x4v c = __builtin_amdgcn_mfma_f32_16x16x32_bf16(aw[0][mt], fA0, bias1v[mt], 0, 0, 0);
            accA[mt] = __builtin_amdgcn_mfma_f32_16x16x32_bf16(aw[1][mt], fA1, c, 0, 0, 0);
        }
        for (int mt = 0; mt < 4; ++mt) {
            f32x4v c = __builtin_amdgcn_mfma_f32_16x16x32_bf16(aw[0][mt], fB0, bias1v[mt], 0, 0, 0);
            accB[mt] = __builtin_amdgcn_mfma_f32_16x16x32_bf16(aw[1][mt], fB1, c, 0, 0, 0);
        }

        // relu + dw2-dot: lane owns 16 hidden units of ONE edge (n=col);
        // in-lane fma then 2-step quad reduce.
        float pA = 0.f, pB = 0.f;
        for (int mt = 0; mt < 4; ++mt)
            for (int r = 0; r < 4; ++r) {
                float vA = accA[mt][r]; vA = vA > 0.f ? vA : 0.f;
                float vB = accB[mt][r]; vB = vB > 0.f ? vB : 0.f;
                pA += vA * w2v[mt][r];
                pB += vB * w2v[mt][r];
            }
        pA += __shfl_xor(pA, 16, 64);
        pA += __shfl_xor(pA, 32, 64);
        pB += __shfl_xor(pB, 16, 64);
        pB += __shfl_xor(pB, 32, 64);

        // lanes 0-15: edge e0+lane (tile A); 16-31: e0+lane (tile B).
        if (lane < 32) {
            float v = (lane < 16 ? pA : pB) + bias2;
            out[e0 + lane] = v;
        }
    }
}

extern "C" void kernel_launch(void* const* d_in, const int* in_sizes, int n_in,
                              void* d_out, int out_size, void* d_ws, size_t ws_size,
                              hipStream_t stream) {
    const float* z_mod = (const float*)d_in[0];
    const int*   eidx  = (const int*)d_in[1];
    const float* w1    = (const float*)d_in[2];
    const float* b1    = (const float*)d_in[3];
    const float* w2    = (const float*)d_in[4];
    const float* b2    = (const float*)d_in[5];
    const float* dw1   = (const float*)d_in[6];
    const float* db1   = (const float*)d_in[7];
    const float* dw2   = (const float*)d_in[8];
    const float* db2   = (const float*)d_in[9];
    float* out = (float*)d_out;

    char*           z8  = (char*)d_ws;                                // 3.2 MB
    unsigned short* scg = (unsigned short*)((char*)d_ws + (size_t)N_NODES * 32);
    // scg: 25000 bf16 (+pad to 50048B read by the stage loop)

    node_proj_kernel<<<512, 256, 0, stream>>>(z_mod, w1, b1, w2, b2, z8, scg);
    // 768 blocks = exactly 3 blocks/CU at 50KB LDS (matches ~12-wave residency)
    edge_dec_kernel<<<768, 256, 0, stream>>>(eidx, z8, scg, dw1, db1, dw2, db2, out);
}